// Round 6
// baseline (401.486 us; speedup 1.0000x reference)
//
#include <hip/hip_runtime.h>
#include <stdint.h>

#define DEPTHC 2
#define DIMC   512
#define FFC    2048
#define INNERC 32
#define VOCABC 8192
#define BC     2
#define LC     512
#define NTOK   1024   // B*L

typedef _Float16 f16;
typedef __attribute__((ext_vector_type(8))) _Float16 f16x8;
typedef __attribute__((ext_vector_type(4))) float f32x4;

__device__ __forceinline__ float2 cmul2(float2 a, float2 b){
    return make_float2(a.x*b.x - a.y*b.y, a.x*b.y + a.y*b.x);
}
__device__ __forceinline__ float2 cadd2(float2 a, float2 b){
    return make_float2(a.x + b.x, a.y + b.y);
}

__device__ __forceinline__ void gl_lds16(const void* g, void* l){
    __builtin_amdgcn_global_load_lds(
        (const __attribute__((address_space(1))) unsigned int*)g,
        (__attribute__((address_space(3))) unsigned int*)l, 16, 0, 0);
}

// ---------------- prep: blocks 0..1 = complex 32x32 inverse; blocks 2.. = fp32->fp16 convert ----
__global__ __launch_bounds__(256) void k_prep(
    const float* __restrict__ s0, const float* __restrict__ s1,
    const float* __restrict__ s2, const float* __restrict__ s3,
    const float* __restrict__ s4,
    f16* __restrict__ d0, f16* __restrict__ d1, f16* __restrict__ d2,
    f16* __restrict__ d3, f16* __restrict__ d4,
    int n0, int n1, int n2, int n3, int n4,
    const float* __restrict__ v_re, const float* __restrict__ v_im,
    const float* __restrict__ h0re, const float* __restrict__ h0im,
    float2* __restrict__ vinv, float2* __restrict__ h0c)
{
    __shared__ float2 M[32][64];
    if (blockIdx.x < 2){
        const int d = blockIdx.x;
        const int tid = threadIdx.x;
        const int c = tid & 63;
        const int wv = tid >> 6;             // 4 waves, rows 8wv..8wv+7
        if (tid < 32) h0c[d*32 + tid] = make_float2(h0re[d*32 + tid], h0im[d*32 + tid]);
#pragma unroll
        for (int rr = 0; rr < 8; ++rr){
            int r = wv*8 + rr;
            float re, im;
            if (c < 32){ re = v_re[d*1024 + r*32 + c]; im = v_im[d*1024 + r*32 + c]; }
            else       { re = (c - 32 == r) ? 1.f : 0.f; im = 0.f; }
            M[r][c] = make_float2(re, im);
        }
        __syncthreads();
#pragma unroll 1
        for (int col = 0; col < 32; ++col){
            float2 prow = M[col][c];
            float pvx = __shfl(prow.x, col, 64);
            float pvy = __shfl(prow.y, col, 64);
            float dm = pvx*pvx + pvy*pvy;
            float ir = pvx/dm, ii = -pvy/dm;
            float2 nv = make_float2(prow.x*ir - prow.y*ii, prow.x*ii + prow.y*ir);
#pragma unroll
            for (int rr = 0; rr < 8; ++rr){
                int r = wv*8 + rr;
                if (r == col) continue;
                float2 f  = M[r][col];
                float2 m0 = M[r][c];
                m0.x -= f.x*nv.x - f.y*nv.y;
                m0.y -= f.x*nv.y + f.y*nv.x;
                M[r][c] = m0;
            }
            __syncthreads();
        }
        if (c >= 32){
#pragma unroll
            for (int rr = 0; rr < 8; ++rr){
                int r = wv*8 + rr;
                float2 dv = M[r][r];
                float dm = dv.x*dv.x + dv.y*dv.y;
                float ir = dv.x/dm, ii = -dv.y/dm;
                float2 m0 = M[r][c];
                vinv[d*1024 + r*32 + (c - 32)] =
                    make_float2(m0.x*ir - m0.y*ii, m0.x*ii + m0.y*ir);
            }
        }
        return;
    }
    long long i = ((long long)(blockIdx.x - 2) * 256 + threadIdx.x) * 4;
    const float* s; f16* d;
    if (i < n0){ s = s0; d = d0; }
    else { i -= n0;
        if (i < n1){ s = s1; d = d1; }
        else { i -= n1;
            if (i < n2){ s = s2; d = d2; }
            else { i -= n2;
                if (i < n3){ s = s3; d = d3; }
                else { i -= n3; if (i >= n4) return; s = s4; d = d4; }
            }
        }
    }
    float4 v = *(const float4*)(s + i);
    union { f16 h[4]; float2 f2; } u;
    u.h[0] = (f16)v.x; u.h[1] = (f16)v.y; u.h[2] = (f16)v.z; u.h[3] = (f16)v.w;
    *(float2*)(d + i) = u.f2;
}

// ---------------- fp16 MFMA GEMM, MTxNT tile, BK=64, global_load_lds staging ----------------
// C[M,N] = A[M,K] * B[N,K]^T. 4 waves in 2x2; wave tile (MT/2)x(NT/2).
// MODE 0: f32 out = acc + bias[col]; MODE 1: f16 split-K partial; MODE 2: f16 silu(acc+bias)
template<int MT, int NT, int MODE>
__global__ __launch_bounds__(256) void k_gemmT(
    const f16* __restrict__ A, const f16* __restrict__ Bw,
    void* __restrict__ C, const float* __restrict__ bias,
    int N, int K, int klen, int partStride)
{
    constexpr int RM = MT/32, RN = NT/32;
    __shared__ __align__(16) f16 As[MT*64];
    __shared__ __align__(16) f16 Bs[NT*64];
    const int tid = threadIdx.x;
    const int m0 = blockIdx.y * MT;
    const int n0 = blockIdx.x * NT;
    const int kbeg = blockIdx.z * klen;
    const int l = tid & 63;
    const int w = tid >> 6;
    const int fr = l & 15;
    const int fq = l >> 4;
    const int wm = (w >> 1) * (MT/2);
    const int wn = (w & 1) * (NT/2);
    const f16* gA = A  + (size_t)(m0 + (tid >> 3)) * K + kbeg + (tid & 7) * 8;
    const f16* gB = Bw + (size_t)(n0 + (tid >> 3)) * K + kbeg + (tid & 7) * 8;
    const size_t rowskip = (size_t)32 * K;
    f16* lA = As + tid * 8;
    f16* lB = Bs + tid * 8;
    f32x4 acc[RM][RN];
#pragma unroll
    for (int i = 0; i < RM; ++i)
#pragma unroll
        for (int j = 0; j < RN; ++j)
            acc[i][j] = (f32x4){0.f, 0.f, 0.f, 0.f};
    for (int kk = 0; kk < klen; kk += 64){
        __syncthreads();
#pragma unroll
        for (int i = 0; i < MT/32; ++i) gl_lds16(gA + i*rowskip, lA + i*2048);
#pragma unroll
        for (int i = 0; i < NT/32; ++i) gl_lds16(gB + i*rowskip, lB + i*2048);
        gA += 64; gB += 64;
        __syncthreads();
#pragma unroll
        for (int h = 0; h < 2; ++h){
            f16x8 af[RM], bf[RN];
#pragma unroll
            for (int i = 0; i < RM; ++i) af[i] = *(const f16x8*)(As + (wm + 16*i + fr) * 64 + h*32 + fq * 8);
#pragma unroll
            for (int j = 0; j < RN; ++j) bf[j] = *(const f16x8*)(Bs + (wn + 16*j + fr) * 64 + h*32 + fq * 8);
#pragma unroll
            for (int i = 0; i < RM; ++i)
#pragma unroll
                for (int j = 0; j < RN; ++j)
                    acc[i][j] = __builtin_amdgcn_mfma_f32_16x16x32_f16(af[i], bf[j], acc[i][j], 0, 0, 0);
        }
    }
#pragma unroll
    for (int i = 0; i < RM; ++i)
#pragma unroll
        for (int j = 0; j < RN; ++j)
#pragma unroll
            for (int r = 0; r < 4; ++r){
                int row = m0 + wm + 16*i + fq*4 + r;
                int col = n0 + wn + 16*j + fr;
                if (MODE == 1){
                    ((f16*)C + (size_t)blockIdx.z * partStride)[(size_t)row * N + col] = (f16)acc[i][j][r];
                } else if (MODE == 0){
                    ((float*)C)[(size_t)row * N + col] = acc[i][j][r] + bias[col];
                } else {
                    float v = acc[i][j][r] + bias[col];
                    ((f16*)C)[(size_t)row * N + col] = (f16)(v / (1.f + __expf(-v)));
                }
            }
}

// ---------------- fused split-K reduce + residual + LN1 + gate proj + nonlinearity ------------
// 2 rows/block, 256 threads, 512 blocks. part: f16 split-K partials (nz slices).
__global__ __launch_bounds__(256) void k_siogate(
    const f16* __restrict__ part, const float* __restrict__ bias,
    const float* __restrict__ res, float* __restrict__ hout,
    const float* __restrict__ g, const float* __restrict__ b,
    const float* __restrict__ wa, const float* __restrict__ wx,
    float2* __restrict__ a_t, float2* __restrict__ xc, int nz)
{
    __shared__ float zs[2][DIMC];
    __shared__ float sc[2][128];
    __shared__ float rs[2][4], rq[2][4];
    const int tid = threadIdx.x;
    const int r0 = blockIdx.x * 2;
    const int c = tid * 2;
    float v0g[2], v1g[2];
#pragma unroll
    for (int gg = 0; gg < 2; ++gg){
        int row = r0 + gg;
        size_t idx = (size_t)row*DIMC + c;
        float v0 = bias[c], v1 = bias[c+1];
        if (res){ v0 += res[idx]; v1 += res[idx+1]; }
        for (int z = 0; z < nz; ++z){
            union { uint32_t u; f16 h[2]; } q;
            q.u = *(const uint32_t*)(part + (size_t)z*(NTOK*DIMC) + idx);
            v0 += (float)q.h[0]; v1 += (float)q.h[1];
        }
        hout[idx] = v0; hout[idx+1] = v1;
        v0g[gg] = v0; v1g[gg] = v1;
        float s = v0 + v1, qq = v0*v0 + v1*v1;
        for (int off = 32; off; off >>= 1){ s += __shfl_down(s, off, 64); qq += __shfl_down(qq, off, 64); }
        if ((tid & 63) == 0){ rs[gg][tid >> 6] = s; rq[gg][tid >> 6] = qq; }
    }
    __syncthreads();
#pragma unroll
    for (int gg = 0; gg < 2; ++gg){
        float S = rs[gg][0]+rs[gg][1]+rs[gg][2]+rs[gg][3];
        float Q = rq[gg][0]+rq[gg][1]+rq[gg][2]+rq[gg][3];
        float m = S / DIMC;
        float rst = rsqrtf(Q / DIMC - m*m + 1e-5f);
        zs[gg][c]   = (v0g[gg] - m)*rst*g[c]   + b[c];
        zs[gg][c+1] = (v1g[gg] - m)*rst*g[c+1] + b[c+1];
    }
    __syncthreads();
    // gate projections: 256 tasks = 2 rows x 128 outputs
    {
        const int rr = tid >> 7;           // wave-uniform
        const int o  = tid & 127;
        const float* wrow = (o < 64) ? (wa + (size_t)o * DIMC) : (wx + (size_t)(o - 64) * DIMC);
        float dot = 0.f;
        for (int cc = 0; cc < DIMC; cc += 4){
            float4 wv = *(const float4*)(wrow + cc);
            float4 zv = *(const float4*)(&zs[rr][cc]);
            dot += wv.x*zv.x + wv.y*zv.y + wv.z*zv.z + wv.w*zv.w;
        }
        sc[rr][o] = dot;
    }
    __syncthreads();
    if (tid < 128){
        int rr = tid >> 6, which = (tid >> 5) & 1, k = tid & 31;
        int row = r0 + rr;
        int bb = row >> 9, t = row & 511;
        if (which == 0){
            float re = sc[rr][2*k], im = sc[rr][2*k + 1];
            float m2 = re*re + im*im;
            float sa = rsqrtf(m2) * (m2 / (1.f + m2));
            a_t[(size_t)(bb*INNERC + k)*LC + t] = make_float2(re*sa, im*sa);
        } else {
            float xr2 = sc[rr][64 + 2*k], xi2 = sc[rr][64 + 2*k + 1];
            float mx = xr2*xr2 + xi2*xi2;
            float sx = sqrtf(mx);
            xc[(size_t)row*INNERC + k] = make_float2(xr2*sx, xi2*sx);
        }
    }
}

// ---------------- split-K reduce + final LayerNorm -> fp16 (one row/block, f16 partials) --------
__global__ __launch_bounds__(128) void k_red_ln(
    const f16* __restrict__ part, const float* __restrict__ bias,
    const float* __restrict__ res, const float* __restrict__ g,
    const float* __restrict__ b, f16* __restrict__ out, int n, int nz)
{
    int row = blockIdx.x;
    int tid = threadIdx.x;
    __shared__ float sw[2], qw[2];
    float v[4]; float s = 0.f, q = 0.f;
#pragma unroll
    for (int j = 0; j < 4; ++j){
        int c = tid + 128*j;
        int idx = row*DIMC + c;
        float t = bias[c] + res[idx];
        for (int z = 0; z < nz; ++z) t += (float)part[(size_t)z * n + idx];
        v[j] = t; s += t; q += t*t;
    }
    for (int off = 32; off; off >>= 1){ s += __shfl_down(s, off, 64); q += __shfl_down(q, off, 64); }
    if ((tid & 63) == 0){ sw[tid >> 6] = s; qw[tid >> 6] = q; }
    __syncthreads();
    float S = sw[0] + sw[1], Q = qw[0] + qw[1];
    float m = S / DIMC;
    float rstd = rsqrtf(Q / DIMC - m*m + 1e-5f);
#pragma unroll
    for (int j = 0; j < 4; ++j){
        int c = tid + 128*j;
        out[(size_t)row*DIMC + c] = (f16)((v[j] - m)*rstd*g[c] + b[c]);
    }
}

// ---------------- fused wprime + scan: e[t] = a[t]*(e[t-1] + Vinv@xroll[t]) ----------------
__global__ __launch_bounds__(64) void k_scan(
    const float2* __restrict__ a_t, const float2* __restrict__ xc,
    const float2* __restrict__ vinv, const float2* __restrict__ h0c,
    float2* __restrict__ e)
{
    int bk = blockIdx.x;   // b*32 + k
    int l = threadIdx.x;   // 0..63, each owns 8 consecutive t
    int bb = bk >> 5, k = bk & 31;
    float2 vrow[32];
#pragma unroll
    for (int o = 0; o < 32; ++o) vrow[o] = vinv[k*32 + o];
    int base = bk * LC + l * 8;
    float2 av[8], wv[8];
#pragma unroll
    for (int j = 0; j < 8; ++j) av[j] = a_t[base + j];
#pragma unroll
    for (int j = 0; j < 8; ++j){
        int t = l*8 + j;
        const float2* src = (t == 0) ? h0c : (xc + (size_t)(bb*LC + t - 1) * INNERC);
        float2 acc = make_float2(0.f, 0.f);
#pragma unroll
        for (int o = 0; o < 32; o += 2){
            float4 qq = *(const float4*)(src + o);
            acc.x += vrow[o].x*qq.x - vrow[o].y*qq.y;
            acc.y += vrow[o].x*qq.y + vrow[o].y*qq.x;
            acc.x += vrow[o+1].x*qq.z - vrow[o+1].y*qq.w;
            acc.y += vrow[o+1].x*qq.w + vrow[o+1].y*qq.z;
        }
        wv[j] = acc;
    }
    float2 A = make_float2(1.f, 0.f), Bc = make_float2(0.f, 0.f);
#pragma unroll
    for (int j = 0; j < 8; ++j){
        Bc = cmul2(av[j], cadd2(Bc, wv[j]));
        A  = cmul2(av[j], A);
    }
    for (int off = 1; off < 64; off <<= 1){
        float Apx = __shfl_up(A.x,  off, 64), Apy = __shfl_up(A.y,  off, 64);
        float Bpx = __shfl_up(Bc.x, off, 64), Bpy = __shfl_up(Bc.y, off, 64);
        if (l >= off){
            float2 Ap = make_float2(Apx, Apy), Bp = make_float2(Bpx, Bpy);
            Bc = cadd2(cmul2(A, Bp), Bc);
            A  = cmul2(A, Ap);
        }
    }
    float ex = __shfl_up(Bc.x, 1, 64), ey = __shfl_up(Bc.y, 1, 64);
    float2 ecur = (l == 0) ? make_float2(0.f, 0.f) : make_float2(ex, ey);
    size_t obase = ((size_t)bb*LC + l*8) * INNERC + k;
#pragma unroll
    for (int j = 0; j < 8; ++j){
        ecur = cmul2(av[j], cadd2(ecur, wv[j]));
        e[obase + (size_t)j * INNERC] = ecur;
    }
}

// ---------------- hr = Re(V*e)+Re(xc); val = hr@w_ol^T + res; hout=val; zout=LN2(val) f16 ----------------
__global__ __launch_bounds__(128) void k_siout_ln(
    const float2* __restrict__ e, const float2* __restrict__ xc,
    const float* __restrict__ vre, const float* __restrict__ vim,
    const float* __restrict__ wol, const float* __restrict__ res,
    const float* __restrict__ g2, const float* __restrict__ b2,
    float* __restrict__ hout, f16* __restrict__ zout)
{
    int bt = blockIdx.x;
    int tid = threadIdx.x;
    __shared__ float hr[INNERC];
    __shared__ float2 er[INNERC];
    __shared__ float sw[2], qw[2];
    if (tid < 32) er[tid] = e[(size_t)bt*INNERC + tid];
    __syncthreads();
    if (tid < 32){
        const float* vrr = vre + tid*INNERC;
        const float* vir = vim + tid*INNERC;
        float acc = xc[(size_t)bt*INNERC + tid].x;
#pragma unroll
        for (int k2 = 0; k2 < 32; ++k2) acc += vrr[k2]*er[k2].x - vir[k2]*er[k2].y;
        hr[tid] = acc;
    }
    __syncthreads();
    float v[4]; float s = 0.f, q = 0.f;
#pragma unroll
    for (int j = 0; j < 4; ++j){
        int n = tid + 128*j;
        float val = res[(size_t)bt*DIMC + n];
        const float* wr = wol + (size_t)n * INNERC;
#pragma unroll
        for (int i = 0; i < 32; ++i) val += hr[i]*wr[i];
        hout[(size_t)bt*DIMC + n] = val;
        v[j] = val; s += val; q += val*val;
    }
    for (int off = 32; off; off >>= 1){ s += __shfl_down(s, off, 64); q += __shfl_down(q, off, 64); }
    if ((tid & 63) == 0){ sw[tid >> 6] = s; qw[tid >> 6] = q; }
    __syncthreads();
    float S = sw[0] + sw[1], Q = qw[0] + qw[1];
    float m = S / DIMC;
    float rstd = rsqrtf(Q / DIMC - m*m + 1e-5f);
#pragma unroll
    for (int j = 0; j < 4; ++j){
        int n = tid + 128*j;
        zout[(size_t)bt*DIMC + n] = (f16)((v[j] - m)*rstd*g2[n] + b2[n]);
    }
}

extern "C" void kernel_launch(void* const* d_in, const int* in_sizes, int n_in,
                              void* d_out, int out_size, void* d_ws, size_t ws_size,
                              hipStream_t stream)
{
    const float* x     = (const float*)d_in[0];
    const float* w_in  = (const float*)d_in[1];
    const float* b_in  = (const float*)d_in[2];
    const float* ln1_g = (const float*)d_in[3];
    const float* ln1_b = (const float*)d_in[4];
    const float* wa    = (const float*)d_in[5];
    const float* wx    = (const float*)d_in[6];
    const float* v_re  = (const float*)d_in[7];
    const float* v_im  = (const float*)d_in[8];
    const float* h0_re = (const float*)d_in[9];
    const float* h0_im = (const float*)d_in[10];
    const float* w_ol  = (const float*)d_in[11];
    const float* ln2_g = (const float*)d_in[12];
    const float* ln2_b = (const float*)d_in[13];
    const float* w1    = (const float*)d_in[14];
    const float* b1    = (const float*)d_in[15];
    const float* w2    = (const float*)d_in[16];
    const float* b2    = (const float*)d_in[17];
    const float* lnl_g = (const float*)d_in[18];
    const float* lnl_b = (const float*)d_in[19];
    const float* w_out = (const float*)d_in[20];
    const float* b_out = (const float*)d_in[21];

    char* p = (char*)d_ws;
    f16* xb   = (f16*)p;   p += (size_t)NTOK * VOCABC * 2;
    f16* wib  = (f16*)p;   p += (size_t)DIMC * VOCABC * 2;
    f16* wob  = (f16*)p;   p += (size_t)VOCABC * DIMC * 2;
    f16* w1b  = (f16*)p;   p += (size_t)DEPTHC * FFC * DIMC * 2;
    f16* w2b  = (f16*)p;   p += (size_t)DEPTHC * DIMC * FFC * 2;
    float* h1 = (float*)p; p += (size_t)NTOK * DIMC * 4;
    float* h2 = (float*)p; p += (size_t)NTOK * DIMC * 4;
    float* h3 = (float*)p; p += (size_t)NTOK * DIMC * 4;
    f16* zb   = (f16*)p;   p += (size_t)NTOK * DIMC * 2;
    f16* ffb  = (f16*)p;   p += (size_t)NTOK * FFC * 2;
    f16* pbuf = (f16*)p;   p += (size_t)8 * NTOK * DIMC * 2;
    float2* a_t = (float2*)p; p += (size_t)BC * INNERC * LC * 8;
    float2* xc  = (float2*)p; p += (size_t)NTOK * INNERC * 8;
    float2* ev  = (float2*)p; p += (size_t)NTOK * INNERC * 8;
    float2* vinv = (float2*)p; p += (size_t)DEPTHC * INNERC * INNERC * 8;
    float2* h0c  = (float2*)p; p += (size_t)DEPTHC * INNERC * 8;

    // prep: inverse (blocks 0..1, hidden) + fp32->fp16 converts (x, w_in, w1, w2, w_out)
    {
        const int n0 = NTOK*VOCABC, n1 = DIMC*VOCABC, n2 = DEPTHC*FFC*DIMC,
                  n3 = DEPTHC*DIMC*FFC, n4 = VOCABC*DIMC;
        int blocks = (n0 + n1 + n2 + n3 + n4) / 1024 + 2;
        k_prep<<<blocks, 256, 0, stream>>>(x, w_in, w1, w2, w_out,
                                           xb, wib, w1b, w2b, wob, n0, n1, n2, n3, n4,
                                           v_re, v_im, h0_re, h0_im, vinv, h0c);
    }

    // in-proj: x @ w_in^T (128x128 tile, split-K=8, f16 partials)
    {
        dim3 g(DIMC/128, NTOK/128, 8);
        k_gemmT<128,128,1><<<g, 256, 0, stream>>>(xb, wib, pbuf, nullptr, DIMC, VOCABC, VOCABC/8, NTOK*DIMC);
    }

    for (int d = 0; d < DEPTHC; ++d){
        float* cur = (d == 0) ? h1 : h3;   // layer input (reduced, written by siogate)
        float* hb  = h2;                    // sio+residual out
        const float* redBias = (d == 0) ? b_in : (b2 + (d-1)*DIMC);
        const float* redRes  = (d == 0) ? nullptr : h2;
        const int nz = (d == 0) ? 8 : 4;
        k_siogate<<<NTOK/2, 256, 0, stream>>>(pbuf, redBias, redRes, cur,
                                              ln1_g + d*DIMC, ln1_b + d*DIMC,
                                              wa + (size_t)d*2*INNERC*DIMC,
                                              wx + (size_t)d*2*INNERC*DIMC, a_t, xc, nz);
        k_scan<<<BC*INNERC, 64, 0, stream>>>(a_t, xc, vinv + d*INNERC*INNERC, h0c + d*INNERC, ev);
        k_siout_ln<<<NTOK, 128, 0, stream>>>(ev, xc, v_re + d*INNERC*INNERC, v_im + d*INNERC*INNERC,
                                             w_ol + (size_t)d*DIMC*INNERC, cur,
                                             ln2_g + d*DIMC, ln2_b + d*DIMC, hb, zb);
        // FFN1: 128x128 tile, silu fused, f16 out
        {
            dim3 g(FFC/128, NTOK/128, 1);
            k_gemmT<128,128,2><<<g, 256, 0, stream>>>(zb, w1b + (size_t)d*FFC*DIMC, ffb, b1 + d*FFC,
                                                      FFC, DIMC, DIMC, 0);
        }
        // FFN2: 128x128 tile, split-K=4, f16 partials
        {
            dim3 g(DIMC/128, NTOK/128, 4);
            k_gemmT<128,128,1><<<g, 256, 0, stream>>>(ffb, w2b + (size_t)d*DIMC*FFC, pbuf, nullptr,
                                                      DIMC, FFC, FFC/4, NTOK*DIMC);
        }
    }
    // final: reduce(4) + residual + LN -> zb (f16)
    k_red_ln<<<NTOK, 128, 0, stream>>>(pbuf, b2 + (DEPTHC-1)*DIMC, h2, lnl_g, lnl_b, zb, NTOK*DIMC, 4);
    // out = zb @ w_out^T + b_out  (128x128 tile)
    {
        dim3 g(VOCABC/128, NTOK/128, 1);
        k_gemmT<128,128,0><<<g, 256, 0, stream>>>(zb, wob, (float*)d_out, b_out, VOCABC, DIMC, DIMC, 0);
    }
    (void)in_sizes; (void)n_in; (void)out_size; (void)ws_size;
}